// Round 15
// baseline (648.640 us; speedup 1.0000x reference)
//
#include <hip/hip_runtime.h>

typedef unsigned short u16;
typedef unsigned int u32;
typedef short bf16x8 __attribute__((ext_vector_type(8)));
typedef float f32x4 __attribute__((ext_vector_type(4)));

#define T_TOK 4096
#define DM 2048
#define DH 4096
#define NE 8
#define MAXSLOT 9216
#define MAXTILE 72

// ws byte offsets (128-slot padding layout)
#define OFF_META   128
#define OFF_TILEE  192
#define OFF_TOPE   512
#define OFF_TOPW   33280
#define OFF_SLOTT  66048
#define OFF_UNION  102912          // tok_slots (y-path) / slot_wt (atomic path)
#define OFF_XBF    139776
#define OFF_W1T    16916992ULL
#define OFF_W2T    151134720ULL
#define OFF_Y      285352448ULL    // y bf16 [MAXSLOT][DM] (y-path) OR h region (atomic path)
#define OFF_H3     323101184ULL    // h chunk region (y-path)
#define NEED_Y     324149760ULL

__device__ __forceinline__ u16 f2bf(float f) {
  union { float f; u32 u; } v; v.f = f;
  u32 r = v.u + 0x7fffu + ((v.u >> 16) & 1u);   // RTNE
  return (u16)(r >> 16);
}

__device__ __forceinline__ float bf2f(u16 h) {
  union { u32 u; float f; } v; v.u = ((u32)h) << 16; return v.f;
}

__device__ __forceinline__ float f4c(const float4& v, int c) {
  return c == 0 ? v.x : c == 1 ? v.y : c == 2 ? v.z : v.w;
}

__device__ __forceinline__ void gl_lds16(const u16* g, u16* l) {
  typedef __attribute__((address_space(1))) const u32 gu32;
  typedef __attribute__((address_space(3))) u32 lu32;
  __builtin_amdgcn_global_load_lds((gu32*)(const void*)g, (lu32*)(void*)l, 16, 0, 0);
}

// branchless exact-GELU via A&S 7.1.26 erf (|err| < 1.5e-7)
__device__ __forceinline__ float gelu_f(float v) {
  float x = v * 0.70710678118654752f;
  float ax = fabsf(x);
  float t = 1.0f / fmaf(0.3275911f, ax, 1.0f);
  float p = t * fmaf(t, fmaf(t, fmaf(t, fmaf(t, 1.061405429f, -1.453152027f),
                                     1.421413741f), -0.284496736f), 0.254829592f);
  float er = 1.0f - p * __expf(-x * x);
  er = copysignf(er, x);
  return 0.5f * v * (1.0f + er);
}

// ---------------- prep mega-kernel (512 threads): transpose + router+convert ----
// blocks [0,2048)    : W1 transpose, 64k x 512n per block -> per k-row TWO
//   back-to-back 1KB loads = 2KB contiguous DRAM bursts (theory #7: burst len).
// blocks [2048,4096) : W2 transpose, same structure.
// blocks [4096,4608) : router (8 waves = 8 tokens/block) + x->bf16 write.
// Output blocked image is byte-identical to the verified layout (GEMM swizzle
// pre-baked); only the T_s-internal slot swizzle differs (matched both sides).
__global__ __launch_bounds__(512) void prep_kernel(
    const float* __restrict__ x, const float* __restrict__ rw,
    const float* __restrict__ w1, const float* __restrict__ w2,
    int* __restrict__ counts, int* __restrict__ top_e, float* __restrict__ top_w,
    u16* __restrict__ xbf, u16* __restrict__ w1t, u16* __restrict__ w2t)
{
  __shared__ u16 T_s[512][64];   // 64 KB; rows = n-local (512), 8 slots x 8 bf16
  int bid = blockIdx.x;
  int tid = threadIdx.x;
  if (bid < 4096) {
    int isw1 = (bid < 2048) ? 1 : 0;
    int b = isw1 ? bid : bid - 2048;
    int e = b >> 8, rr = b & 255;
    const float* W; int N, ks, npair;
    if (isw1) { W = w1 + (size_t)e * DM * DH; N = DH; ks = rr >> 3; npair = rr & 7; }
    else      { W = w2 + (size_t)e * DM * DH; N = DM; ks = rr >> 2; npair = rr & 3; }
    int k0 = ks * 64, n0 = npair * 512;

    int w = tid >> 6, l = tid & 63;   // wave w owns k-rows k0+8w..+7
    const float* src = W + (size_t)(k0 + 8 * w) * N + n0 + 4 * l;
    float4 v[16];                      // v[2i+q] = row i, quarter q (cols q*256+4l..)
#pragma unroll
    for (int i = 0; i < 8; ++i) {
      v[2 * i + 0] = *(const float4*)(src + (size_t)i * N);
      v[2 * i + 1] = *(const float4*)(src + (size_t)i * N + 256);
    }
    // pack: k-chunk j = w (8 k's); write col nloc's chunk as one uint4
#pragma unroll
    for (int q = 0; q < 2; ++q) {
#pragma unroll
      for (int c = 0; c < 4; ++c) {
        uint4 pkv;
        pkv.x = (u32)f2bf(f4c(v[0 + q], c)) | ((u32)f2bf(f4c(v[2 + q], c)) << 16);
        pkv.y = (u32)f2bf(f4c(v[4 + q], c)) | ((u32)f2bf(f4c(v[6 + q], c)) << 16);
        pkv.z = (u32)f2bf(f4c(v[8 + q], c)) | ((u32)f2bf(f4c(v[10 + q], c)) << 16);
        pkv.w = (u32)f2bf(f4c(v[12 + q], c)) | ((u32)f2bf(f4c(v[14 + q], c)) << 16);
        int nloc = q * 256 + 4 * l + c;
        int slot = (w + (nloc >> 2)) & 7;
        *(uint4*)&T_s[nloc][slot * 8] = pkv;
      }
    }
    __syncthreads();
    // phase 2: two 16KB kstep-pair images (img = n-half), contiguous writes
    int img = tid >> 8;                // 0,1
    int t2 = tid & 255;
    int lr = t2 >> 2;
    int s  = t2 & 3;
    int kf = s ^ ((t2 >> 3) & 3);      // baked GEMM swizzle
    int ntile = npair * 2 + img;
    u16* WtT = isw1
        ? w1t + ((size_t)((e * 16 + ntile) * 64 + ks * 2)) * 8192
        : w2t + ((size_t)((e * 8 + ntile) * 128 + ks * 2)) * 8192;
#pragma unroll
    for (int ks_l = 0; ks_l < 2; ++ks_l) {
      int J = ks_l * 4 + kf;
#pragma unroll
      for (int q2 = 0; q2 < 4; ++q2) {
        int nloc = img * 256 + q2 * 64 + lr;
        int slot = (J + (nloc >> 2)) & 7;
        uint4 vv = *(const uint4*)&T_s[nloc][slot * 8];
        *(uint4*)(WtT + (size_t)ks_l * 8192 + q2 * 2048 + t2 * 8) = vv;
      }
    }
  } else {
    // ---- router + fused x->bf16 (8 waves = 8 tokens per block) ----
    int wv = tid >> 6;
    int lane = tid & 63;
    int t = (bid - 4096) * 8 + wv;
    const float4* xr = (const float4*)(x + (size_t)t * DM);
    const float4* rw4 = (const float4*)rw;
    float acc[NE];
#pragma unroll
    for (int e = 0; e < NE; ++e) acc[e] = 0.f;
    for (int i = 0; i < 8; ++i) {
      int d4 = i * 64 + lane;
      float4 xv = xr[d4];
      uint2 pk;
      pk.x = f2bf(xv.x) | ((u32)f2bf(xv.y) << 16);
      pk.y = f2bf(xv.z) | ((u32)f2bf(xv.w) << 16);
      *(uint2*)(xbf + (size_t)t * DM + d4 * 4) = pk;
#pragma unroll
      for (int j = 0; j < 4; ++j) {
        int d = 4 * d4 + j;
        float4 r0 = rw4[d * 2];
        float4 r1 = rw4[d * 2 + 1];
        float xs = f4c(xv, j);
        acc[0] += xs * r0.x; acc[1] += xs * r0.y; acc[2] += xs * r0.z; acc[3] += xs * r0.w;
        acc[4] += xs * r1.x; acc[5] += xs * r1.y; acc[6] += xs * r1.z; acc[7] += xs * r1.w;
      }
    }
#pragma unroll
    for (int off = 32; off > 0; off >>= 1)
#pragma unroll
      for (int e = 0; e < NE; ++e) acc[e] += __shfl_xor(acc[e], off, 64);
    if (lane == 0) {
      int e0 = 0; float l0 = acc[0];
#pragma unroll
      for (int e = 1; e < NE; ++e) if (acc[e] > l0) { l0 = acc[e]; e0 = e; }
      int e1 = -1; float l1 = -3.0e38f;
#pragma unroll
      for (int e = 0; e < NE; ++e) if (e != e0 && acc[e] > l1) { l1 = acc[e]; e1 = e; }
      float w0 = 1.f / (1.f + expf(l1 - l0));
      float w1v = 1.f - w0;
      top_e[t * 2 + 0] = e0; top_e[t * 2 + 1] = e1;
      top_w[t * 2 + 0] = w0; top_w[t * 2 + 1] = w1v;
      atomicAdd(&counts[e0], 1);
      atomicAdd(&counts[e1], 1);
    }
  }
}

// ---------------- scan + scatter merged (1 block; LDS-atomic cursors) ----------
__global__ void scan_scatter_kernel(int* __restrict__ wsI, int useY)
{
  int* counts = wsI;
  int* offs   = wsI + 16;
  int* meta   = wsI + (OFF_META / 4);
  int* tile_e = wsI + (OFF_TILEE / 4);
  int* top_e  = wsI + (OFF_TOPE / 4);
  float* top_w = (float*)(wsI + (OFF_TOPW / 4));
  int* slot_token = wsI + (OFF_SLOTT / 4);
  int* tok_slots  = wsI + (OFF_UNION / 4);
  float* slot_wt  = (float*)(wsI + (OFF_UNION / 4));
  __shared__ int s_off[9];
  __shared__ int s_cur[8];
  if (threadIdx.x == 0) {
    int o = 0;
    for (int e = 0; e < NE; ++e) {
      offs[e] = o; s_off[e] = o; s_cur[e] = o;
      o += (counts[e] + 127) & ~127;
    }
    offs[8] = o; s_off[8] = o;
    meta[0] = o >> 7;
  }
  __syncthreads();
  int nt = s_off[8] >> 7;
  for (int i = threadIdx.x; i < MAXTILE; i += blockDim.x) {
    int e = -1;
    if (i < nt) {
      for (int j = 0; j < NE; ++j)
        if (i * 128 >= s_off[j] && i * 128 < s_off[j + 1]) e = j;
    }
    tile_e[i] = e;
  }
  for (int i = threadIdx.x; i < MAXSLOT; i += blockDim.x) {
    slot_token[i] = -1;
    slot_wt[i] = 0.f;
  }
  __syncthreads();
  // scatter (any assignment order is valid; inverse map written here too)
  for (int t = threadIdx.x; t < T_TOK; t += blockDim.x) {
#pragma unroll
    for (int k = 0; k < 2; ++k) {
      int e = top_e[t * 2 + k];
      int pos = atomicAdd(&s_cur[e], 1);
      slot_token[pos] = t;
      if (useY) tok_slots[t * 2 + k] = pos;
      else      slot_wt[pos] = top_w[t * 2 + k];
    }
  }
}

// ---------------- 128x256 triple-buffer GEMM, fat-hoisted phases ----------------
// 4 waves, wave tile 128x64 (acc 4x8). BK=32, LDS = 3 x (A 8KB + B 16KB) = 72KB
// -> 2 co-resident blocks/CU. One barrier-pair per k-step (32 MFMA), fragment
// reads hoisted after the MFMA cluster. B reads BLOCKED weight layout (16 KB
// contiguous per k-step at base + tid*16, swizzle pre-baked). All staging via
// global_load_lds (HOMOGENEOUS vmcnt window -- round-12 lesson: do not mix
// gl_lds with register loads inside one counted-gate window).
// Ledger: phase t stages step t+2 into buf(t+2)%3 (2-phase WAR margin); GATE6
// drains step t+1's 6 loads before the opening barrier. Tail: GATE0 at NK-2.

#define GATEN(n) asm volatile("s_waitcnt vmcnt(" #n ")" ::: "memory")
#define NOGATE ((void)0)
#define NOSTG  ((void)0)
#define NORD   ((void)0)

#define SA_(PA, KO) do { \
  gl_lds16(aptr0 + (KO), &PA[wid * 16][0]);        \
  gl_lds16(aptr1 + (KO), &PA[64 + wid * 16][0]); } while (0)
#define SBALL(PB, KS) do { \
  gl_lds16(bptrT + (size_t)(KS) * 8192,        &PB[wid * 16][0]);        \
  gl_lds16(bptrT + (size_t)(KS) * 8192 + 2048, &PB[64 + wid * 16][0]);   \
  gl_lds16(bptrT + (size_t)(KS) * 8192 + 4096, &PB[128 + wid * 16][0]);  \
  gl_lds16(bptrT + (size_t)(KS) * 8192 + 6144, &PB[192 + wid * 16][0]); } while (0)

#define RDAF8(P)                                                        \
  _Pragma("unroll")                                                     \
  for (int i_ = 0; i_ < 8; ++i_)                                        \
    af[i_] = *(const bf16x8*)&P[i_ * 16 + lrow][sp8]
#define RDBF(P)                                                         \
  _Pragma("unroll")                                                     \
  for (int n_ = 0; n_ < 4; ++n_)                                        \
    bfr[n_] = *(const bf16x8*)&P[wn + n_ * 16 + lrow][sp8]

#define PHF(STG, GATE, RD) do {                                         \
  STG;                                                                  \
  GATE;                                                                 \
  __builtin_amdgcn_s_barrier();                                         \
  asm volatile("s_waitcnt lgkmcnt(0)" ::: "memory");                    \
  __builtin_amdgcn_sched_barrier(0);                                    \
  __builtin_amdgcn_s_setprio(1);                                        \
  _Pragma("unroll")                                                     \
  for (int nf = 0; nf < 4; ++nf)                                        \
    _Pragma("unroll")                                                   \
    for (int mf = 0; mf < 8; ++mf)                                      \
      acc[nf][mf] = __builtin_amdgcn_mfma_f32_16x16x32_bf16(            \
          bfr[nf], af[mf], acc[nf][mf], 0, 0, 0);                       \
  __builtin_amdgcn_s_setprio(0);                                        \
  RD;                                                                   \
  __builtin_amdgcn_s_barrier();                                         \
  __builtin_amdgcn_sched_barrier(0);                                    \
} while (0)

template<int MODE, int EPI>
__global__ __launch_bounds__(256, 2) void gemm_tb(
    const u16* __restrict__ Wt, const float* __restrict__ bias,
    const u16* __restrict__ Abase,
    u16* __restrict__ Hout, u16* __restrict__ Ybuf, float* __restrict__ Out,
    const int* __restrict__ slot_token, const float* __restrict__ slot_wt,
    const int* __restrict__ tile_e, const int* __restrict__ meta,
    int tile0, int mtc)
{
  constexpr int KD = (MODE == 0) ? DM : DH;
  constexpr int ND = (MODE == 0) ? DH : DM;
  constexpr int NT = ND / 256;
  constexpr int NK = KD / 32;

  __shared__ u16 A_s[3][128][32];   // [buf][row][32 bf16], 4x16B slots/row
  __shared__ u16 B_s[3][256][32];

  int nwg = gridDim.x;
  int flat = blockIdx.x;
  int q8 = nwg >> 3, rr = nwg & 7;
  int xcd = flat & 7, i0 = flat >> 3;
  int wg = (xcd < rr ? xcd * (q8 + 1) : rr * (q8 + 1) + (xcd - rr) * q8) + i0;
  // mloc-major: the NT n-tile blocks of one m-tile are consecutive -> concurrent
  int mloc = wg / NT;
  int ntile = wg % NT;
  int mt = tile0 + mloc;
  if (mt >= meta[0]) return;
  int e = tile_e[mt];
  int n0 = ntile * 256;

  const int tid = threadIdx.x;
  const int lane = tid & 63;
  const int wid = tid >> 6;
  const int lrow = lane & 15;
  const int g = lane >> 4;
  const int sp8 = (g ^ ((lrow >> 1) & 3)) << 3;   // swizzled 16B slot (read side)
  const int wn = wid << 6;                        // 0 / 64 / 128 / 192

  // A staging: thread stages rows srow(+64); source pre-swizzled (rule 21)
  const int srow = tid >> 2;
  const int swz = ((tid & 3) ^ ((tid >> 3) & 3)) << 3;

  const u16 *aptr0, *aptr1;
  if (MODE == 0) {
    int t0 = slot_token[mt * 128 + srow];       if (t0 < 0) t0 = 0;
    int t1 = slot_token[mt * 128 + 64 + srow];  if (t1 < 0) t1 = 0;
    aptr0 = Abase + (size_t)t0 * KD + swz;
    aptr1 = Abase + (size_t)t1 * KD + swz;
  } else {
    aptr0 = Abase + (size_t)(mloc * 128 + srow) * KD + swz;
    aptr1 = Abase + (size_t)(mloc * 128 + 64 + srow) * KD + swz;
  }
  // B staging: blocked layout, 16 KB contiguous per k-step, base + tid*16B
  const u16* bptrT = Wt + ((size_t)(e * NT + ntile) * NK) * 8192 + tid * 8;

  f32x4 acc[4][8] = {};   // [nf][mf], D^T (operand-swapped); wave owns full 128 M
  bf16x8 af[8], bfr[4];

  u16 (*pA0)[32] = A_s[0]; u16 (*pA1)[32] = A_s[1]; u16 (*pA2)[32] = A_s[2];
  u16 (*pB0)[32] = B_s[0]; u16 (*pB1)[32] = B_s[1]; u16 (*pB2)[32] = B_s[2];

  // prologue: stage steps 0,1 (12 loads), drain step0, preload step0 frags
  SA_(pA0, 0); SBALL(pB0, 0);
  SA_(pA1, 32); SBALL(pB1, 1);
  GATEN(6);
  __builtin_amdgcn_s_barrier();
  __builtin_amdgcn_sched_barrier(0);
  RDAF8(pA0);
  RDBF(pB0);

  for (int t = 0; t < NK - 2; ++t) {
    int ko = (t + 2) * 32;
    // fat phase: MFMA step t; stage step t+2 -> pA2/pB2; read frags step t+1
    PHF(SA_(pA2, ko); SBALL(pB2, t + 2), GATEN(6),
        RDAF8(pA1); RDBF(pB1));
    // rotate cur<-next<-nn<-cur
    u16 (*tA)[32] = pA0; pA0 = pA1; pA1 = pA2; pA2 = tA;
    u16 (*tB)[32] = pB0; pB0 = pB1; pB1 = pB2; pB2 = tB;
  }
  // tail: step NK-2 (drain last loads before reading step NK-1 frags), step NK-1
  PHF(NOSTG, GATEN(0), RDAF8(pA1); RDBF(pB1));
  PHF(NOSTG, NOGATE, NORD);

  // epilogue: n = n0 + wn + nf*16 + rb + i ; row = mf*16 + lrow (wave owns all M)
  const int rb = g << 2;
  float4 bias4[4];
#pragma unroll
  for (int nf = 0; nf < 4; ++nf)
    bias4[nf] = *(const float4*)&bias[e * ND + n0 + wn + nf * 16 + rb];

  if constexpr (MODE == 0) {
#pragma unroll
    for (int mf = 0; mf < 8; ++mf) {
      u16* hp = Hout + (size_t)(mloc * 128 + mf * 16 + lrow) * DH + n0 + wn + rb;
#pragma unroll
      for (int nf = 0; nf < 4; ++nf) {
        float v0 = gelu_f(acc[nf][mf][0] + bias4[nf].x);
        float v1 = gelu_f(acc[nf][mf][1] + bias4[nf].y);
        float v2 = gelu_f(acc[nf][mf][2] + bias4[nf].z);
        float v3 = gelu_f(acc[nf][mf][3] + bias4[nf].w);
        uint2 pk;
        pk.x = f2bf(v0) | ((u32)f2bf(v1) << 16);
        pk.y = f2bf(v2) | ((u32)f2bf(v3) << 16);
        *(uint2*)(hp + nf * 16) = pk;
      }
    }
  } else if constexpr (EPI == 0) {
#pragma unroll
    for (int mf = 0; mf < 8; ++mf) {
      u16* yp = Ybuf + (size_t)(mt * 128 + mf * 16 + lrow) * DM + n0 + wn + rb;
#pragma unroll
      for (int nf = 0; nf < 4; ++nf) {
        float v0 = acc[nf][mf][0] + bias4[nf].x;
        float v1 = acc[nf][mf][1] + bias4[nf].y;
        float v2 = acc[nf][mf][2] + bias4[nf].z;
        float v3 = acc[nf][mf][3] + bias4[nf].w;
        uint2 pk;
        pk.x = f2bf(v0) | ((u32)f2bf(v1) << 16);
        pk.y = f2bf(v2) | ((u32)f2bf(v3) << 16);
        *(uint2*)(yp + nf * 16) = pk;
      }
    }
  } else {
#pragma unroll
    for (int mf = 0; mf < 8; ++mf) {
      int gs = mt * 128 + mf * 16 + lrow;
      int tok = slot_token[gs];
      if (tok < 0) continue;
      float wt = slot_wt[gs];
      float* op = Out + (size_t)tok * DM + n0 + wn + rb;
#pragma unroll
      for (int nf = 0; nf < 4; ++nf) {
        atomicAdd(op + nf * 16 + 0, wt * (acc[nf][mf][0] + bias4[nf].x));
        atomicAdd(op + nf * 16 + 1, wt * (acc[nf][mf][1] + bias4[nf].y));
        atomicAdd(op + nf * 16 + 2, wt * (acc[nf][mf][2] + bias4[nf].z));
        atomicAdd(op + nf * 16 + 3, wt * (acc[nf][mf][3] + bias4[nf].w));
      }
    }
  }
}

// ---------------- combine: out[t] = w0*y[s0] + w1*y[s1] ----------------
__global__ __launch_bounds__(256) void combine_kernel(
    const u16* __restrict__ y, const int* __restrict__ tok_slots,
    const float* __restrict__ top_w, float* __restrict__ out)
{
  int t = blockIdx.x;
  int d = threadIdx.x * 8;
  int s0 = tok_slots[t * 2], s1 = tok_slots[t * 2 + 1];
  float w0 = top_w[t * 2], w1 = top_w[t * 2 + 1];
  union { uint4 u; u16 s[8]; } a, b;
  a.u = *(const uint4*)(y + (size_t)s0 * DM + d);
  b.u = *(const uint4*)(y + (size_t)s1 * DM + d);
  float o[8];
#pragma unroll
  for (int j = 0; j < 8; ++j) o[j] = w0 * bf2f(a.s[j]) + w1 * bf2f(b.s[j]);
  float* op = out + (size_t)t * DM + d;
  *(float4*)op = make_float4(o[0], o[1], o[2], o[3]);
  *(float4*)(op + 4) = make_float4(o[4], o[5], o[6], o[7]);
}

extern "C" void kernel_launch(void* const* d_in, const int* in_sizes, int n_in,
                              void* d_out, int out_size, void* d_ws, size_t ws_size,
                              hipStream_t stream) {
  const float* x  = (const float*)d_in[0];
  const float* rw = (const float*)d_in[1];
  const float* w1 = (const float*)d_in[2];
  const float* b1 = (const float*)d_in[3];
  const float* w2 = (const float*)d_in[4];
  const float* b2 = (const float*)d_in[5];
  float* out = (float*)d_out;
  char* ws = (char*)d_ws;

  int* counts = (int*)ws;
  int* meta   = (int*)(ws + OFF_META);
  int* tile_e = (int*)(ws + OFF_TILEE);
  int* top_e  = (int*)(ws + OFF_TOPE);
  float* top_w = (float*)(ws + OFF_TOPW);
  int* slot_token = (int*)(ws + OFF_SLOTT);
  int* tok_slots  = (int*)(ws + OFF_UNION);
  float* slot_wt  = (float*)(ws + OFF_UNION);
  u16* xbf = (u16*)(ws + OFF_XBF);
  u16* w1t = (u16*)(ws + OFF_W1T);
  u16* w2t = (u16*)(ws + OFF_W2T);

  const int useY = (ws_size >= NEED_Y) ? 1 : 0;
  u16* ybuf = (u16*)(ws + OFF_Y);
  u16* hbuf = (u16*)(ws + (useY ? OFF_H3 : OFF_Y));

  hipMemsetAsync(ws, 0, 512, stream);
  if (!useY) hipMemsetAsync(d_out, 0, (size_t)out_size * sizeof(float), stream);

  prep_kernel<<<4608, 512, 0, stream>>>(x, rw, w1, w2, counts, top_e, top_w,
                                        xbf, w1t, w2t);
  scan_scatter_kernel<<<1, 256, 0, stream>>>((int*)ws, useY);

  size_t hoff = useY ? OFF_H3 : OFF_Y;
  size_t avail = ws_size > hoff ? ws_size - hoff : (size_t)DH * 256;
  long ch_slots = (long)(avail / (DH * 2));
  ch_slots = (ch_slots / 128) * 128;
  if (ch_slots > MAXSLOT) ch_slots = MAXSLOT;
  if (ch_slots < 128) ch_slots = 128;
  int mtc = (int)(ch_slots / 128);
  int nchunks = (MAXTILE + mtc - 1) / mtc;

  for (int c = 0; c < nchunks; ++c) {
    int tile0 = c * mtc;
    gemm_tb<0, 0><<<dim3(mtc * (DH / 256)), 256, 0, stream>>>(
        w1t, b1, xbf, hbuf, nullptr, nullptr, slot_token, slot_wt, tile_e, meta,
        tile0, mtc);
    if (useY) {
      gemm_tb<1, 0><<<dim3(mtc * (DM / 256)), 256, 0, stream>>>(
          w2t, b2, hbuf, nullptr, ybuf, nullptr, slot_token, slot_wt, tile_e, meta,
          tile0, mtc);
    } else {
      gemm_tb<1, 1><<<dim3(mtc * (DM / 256)), 256, 0, stream>>>(
          w2t, b2, hbuf, nullptr, nullptr, out, slot_token, slot_wt, tile_e, meta,
          tile0, mtc);
    }
  }
  if (useY)
    combine_kernel<<<T_TOK, 256, 0, stream>>>(ybuf, tok_slots, top_w, out);
}

// Round 16
// 630.215 us; speedup vs baseline: 1.0292x; 1.0292x over previous
//
#include <hip/hip_runtime.h>

typedef unsigned short u16;
typedef unsigned int u32;
typedef short bf16x8 __attribute__((ext_vector_type(8)));
typedef float f32x4 __attribute__((ext_vector_type(4)));

#define T_TOK 4096
#define DM 2048
#define DH 4096
#define NE 8
#define MAXSLOT 9216
#define MAXTILE 72

// ws byte offsets (128-slot padding layout)
#define OFF_META   128
#define OFF_TILEE  192
#define OFF_TOPE   512
#define OFF_TOPW   33280
#define OFF_SLOTT  66048
#define OFF_UNION  102912          // tok_slots (y-path) / slot_wt (atomic path)
#define OFF_XBF    139776
#define OFF_W1T    16916992ULL
#define OFF_W2T    151134720ULL
#define OFF_Y      285352448ULL    // y bf16 [MAXSLOT][DM] (y-path) OR h region (atomic path)
#define OFF_H3     323101184ULL    // h chunk region (y-path)
#define NEED_Y     324149760ULL

__device__ __forceinline__ u16 f2bf(float f) {
  union { float f; u32 u; } v; v.f = f;
  u32 r = v.u + 0x7fffu + ((v.u >> 16) & 1u);   // RTNE
  return (u16)(r >> 16);
}

__device__ __forceinline__ float bf2f(u16 h) {
  union { u32 u; float f; } v; v.u = ((u32)h) << 16; return v.f;
}

__device__ __forceinline__ float f4c(const float4& v, int c) {
  return c == 0 ? v.x : c == 1 ? v.y : c == 2 ? v.z : v.w;
}

__device__ __forceinline__ void gl_lds16(const u16* g, u16* l) {
  typedef __attribute__((address_space(1))) const u32 gu32;
  typedef __attribute__((address_space(3))) u32 lu32;
  __builtin_amdgcn_global_load_lds((gu32*)(const void*)g, (lu32*)(void*)l, 16, 0, 0);
}

// branchless exact-GELU via A&S 7.1.26 erf (|err| < 1.5e-7)
__device__ __forceinline__ float gelu_f(float v) {
  float x = v * 0.70710678118654752f;
  float ax = fabsf(x);
  float t = 1.0f / fmaf(0.3275911f, ax, 1.0f);
  float p = t * fmaf(t, fmaf(t, fmaf(t, fmaf(t, 1.061405429f, -1.453152027f),
                                     1.421413741f), -0.284496736f), 0.254829592f);
  float er = 1.0f - p * __expf(-x * x);
  er = copysignf(er, x);
  return 0.5f * v * (1.0f + er);
}

// ---------------- prep mega-kernel: transpose(blocked layout) + router+convert ----
// blocks [0,8192)    : W1/W2 transpose+bf16 into blocked tile layout (swizzle
//   pre-baked: tiles [e][ntile][kstep] of 16 KB = the LDS staging image the
//   GEMM consumes). float4 reads (16 B/lane); XOR slot swizzle in T_s.
//   ~262 us, 2.2 TB/s: structural floor (7 theories falsified; stop probing).
// blocks [8192,9216) : router (1 wave/token) + x->bf16 write (x already loaded)
__global__ __launch_bounds__(256) void prep_kernel(
    const float* __restrict__ x, const float* __restrict__ rw,
    const float* __restrict__ w1, const float* __restrict__ w2,
    int* __restrict__ counts, int* __restrict__ top_e, float* __restrict__ top_w,
    u16* __restrict__ xbf, u16* __restrict__ w1t, u16* __restrict__ w2t)
{
  __shared__ u16 T_s[256][64];   // 32 KB; rows = n-local, 8 slots x 8 bf16
  int bid = blockIdx.x;
  if (bid < 8192) {
    const float* W; u16* WtT; int N, k0, n0;
    if (bid < 4096) {               // w1: K=2048(64 ksteps), N=4096(16 ntiles)
      int e = bid >> 9, r = bid & 511;
      W = w1 + (size_t)e * DM * DH;
      N = DH; k0 = (r >> 4) * 64; n0 = (r & 15) * 256;
      WtT = w1t + ((size_t)((e * 16 + (r & 15)) * 64 + (r >> 4) * 2)) * 8192;
    } else {                        // w2: K=4096(128 ksteps), N=2048(8 ntiles)
      int b2 = bid - 4096;
      int e = b2 >> 9, r = b2 & 511;
      W = w2 + (size_t)e * DM * DH;
      N = DM; k0 = (r >> 3) * 64; n0 = (r & 7) * 256;
      WtT = w2t + ((size_t)((e * 8 + (r & 7)) * 128 + (r >> 3) * 2)) * 8192;
    }
    int wv = threadIdx.x >> 6, l = threadIdx.x & 63;
    // phase 1: wave wv reads k-rows k0+wv*16 .. +15, lane l cols n0+4l..4l+3
    const float* src = W + (size_t)(k0 + wv * 16) * N + n0 + 4 * l;
    float4 v[16];
#pragma unroll
    for (int i = 0; i < 16; ++i) v[i] = *(const float4*)(src + (size_t)i * N);
    u32 pk[4][8];                   // pk[c][w] = k-pair (2w, 2w+1) of col 4l+c
#pragma unroll
    for (int c = 0; c < 4; ++c)
#pragma unroll
      for (int w = 0; w < 8; ++w)
        pk[c][w] = (u32)f2bf(f4c(v[2 * w], c)) |
                   ((u32)f2bf(f4c(v[2 * w + 1], c)) << 16);
#pragma unroll
    for (int c = 0; c < 4; ++c) {
      int nloc = 4 * l + c;
      int h = (5 * l + c) & 7;      // = (nloc + (nloc>>2)) & 7
#pragma unroll
      for (int jl = 0; jl < 2; ++jl) {
        int j = wv * 2 + jl;        // global k-chunk (8 k each)
        int slot = (j + h) & 7;
        uint4 vv = make_uint4(pk[c][4 * jl + 0], pk[c][4 * jl + 1],
                              pk[c][4 * jl + 2], pk[c][4 * jl + 3]);
        *(uint4*)&T_s[nloc][slot * 8] = vv;
      }
    }
    __syncthreads();
    // phase 2: blocked-tile image write (GEMM swizzle pre-baked)
    int tid = threadIdx.x;
    int lr = tid >> 2;
    int s  = tid & 3;
    int kf = s ^ ((tid >> 3) & 3);       // baked GEMM swizzle
#pragma unroll
    for (int ks_l = 0; ks_l < 2; ++ks_l) {
      int J = ks_l * 4 + kf;
#pragma unroll
      for (int q = 0; q < 4; ++q) {
        int row = q * 64 + lr;
        int slot = (J + row + (row >> 2)) & 7;
        uint4 vv = *(const uint4*)&T_s[row][slot * 8];
        *(uint4*)(WtT + (size_t)ks_l * 8192 + q * 2048 + tid * 8) = vv;
      }
    }
  } else {
    // ---- router + fused x->bf16 ----
    int wv = threadIdx.x >> 6;
    int lane = threadIdx.x & 63;
    int t = (bid - 8192) * 4 + wv;
    const float4* xr = (const float4*)(x + (size_t)t * DM);
    const float4* rw4 = (const float4*)rw;
    float acc[NE];
#pragma unroll
    for (int e = 0; e < NE; ++e) acc[e] = 0.f;
    for (int i = 0; i < 8; ++i) {
      int d4 = i * 64 + lane;
      float4 xv = xr[d4];
      uint2 pk;
      pk.x = f2bf(xv.x) | ((u32)f2bf(xv.y) << 16);
      pk.y = f2bf(xv.z) | ((u32)f2bf(xv.w) << 16);
      *(uint2*)(xbf + (size_t)t * DM + d4 * 4) = pk;
#pragma unroll
      for (int j = 0; j < 4; ++j) {
        int d = 4 * d4 + j;
        float4 r0 = rw4[d * 2];
        float4 r1 = rw4[d * 2 + 1];
        float xs = f4c(xv, j);
        acc[0] += xs * r0.x; acc[1] += xs * r0.y; acc[2] += xs * r0.z; acc[3] += xs * r0.w;
        acc[4] += xs * r1.x; acc[5] += xs * r1.y; acc[6] += xs * r1.z; acc[7] += xs * r1.w;
      }
    }
#pragma unroll
    for (int off = 32; off > 0; off >>= 1)
#pragma unroll
      for (int e = 0; e < NE; ++e) acc[e] += __shfl_xor(acc[e], off, 64);
    if (lane == 0) {
      int e0 = 0; float l0 = acc[0];
#pragma unroll
      for (int e = 1; e < NE; ++e) if (acc[e] > l0) { l0 = acc[e]; e0 = e; }
      int e1 = -1; float l1 = -3.0e38f;
#pragma unroll
      for (int e = 0; e < NE; ++e) if (e != e0 && acc[e] > l1) { l1 = acc[e]; e1 = e; }
      float w0 = 1.f / (1.f + expf(l1 - l0));
      float w1v = 1.f - w0;
      top_e[t * 2 + 0] = e0; top_e[t * 2 + 1] = e1;
      top_w[t * 2 + 0] = w0; top_w[t * 2 + 1] = w1v;
      atomicAdd(&counts[e0], 1);
      atomicAdd(&counts[e1], 1);
    }
  }
}

// ---------------- scan + scatter merged (1 block; LDS-atomic cursors) ----------
__global__ void scan_scatter_kernel(int* __restrict__ wsI, int useY)
{
  int* counts = wsI;
  int* offs   = wsI + 16;
  int* meta   = wsI + (OFF_META / 4);
  int* tile_e = wsI + (OFF_TILEE / 4);
  int* top_e  = wsI + (OFF_TOPE / 4);
  float* top_w = (float*)(wsI + (OFF_TOPW / 4));
  int* slot_token = wsI + (OFF_SLOTT / 4);
  int* tok_slots  = wsI + (OFF_UNION / 4);
  float* slot_wt  = (float*)(wsI + (OFF_UNION / 4));
  __shared__ int s_off[9];
  __shared__ int s_cur[8];
  if (threadIdx.x == 0) {
    int o = 0;
    for (int e = 0; e < NE; ++e) {
      offs[e] = o; s_off[e] = o; s_cur[e] = o;
      o += (counts[e] + 127) & ~127;
    }
    offs[8] = o; s_off[8] = o;
    meta[0] = o >> 7;
  }
  __syncthreads();
  int nt = s_off[8] >> 7;
  for (int i = threadIdx.x; i < MAXTILE; i += blockDim.x) {
    int e = -1;
    if (i < nt) {
      for (int j = 0; j < NE; ++j)
        if (i * 128 >= s_off[j] && i * 128 < s_off[j + 1]) e = j;
    }
    tile_e[i] = e;
  }
  for (int i = threadIdx.x; i < MAXSLOT; i += blockDim.x) {
    slot_token[i] = -1;
    slot_wt[i] = 0.f;
  }
  __syncthreads();
  // scatter (any assignment order is valid; inverse map written here too)
  for (int t = threadIdx.x; t < T_TOK; t += blockDim.x) {
#pragma unroll
    for (int k = 0; k < 2; ++k) {
      int e = top_e[t * 2 + k];
      int pos = atomicAdd(&s_cur[e], 1);
      slot_token[pos] = t;
      if (useY) tok_slots[t * 2 + k] = pos;
      else      slot_wt[pos] = top_w[t * 2 + k];
    }
  }
}

// ---------------- 128x256 triple-buffer GEMM, single-barrier phases ------------
// 4 waves, wave tile 128x64 (acc 4x8). BK=32, LDS = 3 x (A 8KB + B 16KB) = 72KB
// -> 2 co-resident blocks/CU. ONE barrier per k-step (closing barrier removed):
// WAR audit: RD@p reads buf(p+1); the only conflicting writer is STG@p+2
// (writes buf(p+4)=buf(p+1)); bar1@p+1 (STG precedes its phase's bar1) plus
// bar1@p+2 separate them even under +-1 phase wave skew. gl_lds publication:
// GATE (vmcnt6, drains step t+1's 6 loads) + bar1. Frag ds_reads crossing a
// phase are drained by the next phase's lgkmcnt(0). Tail: GATE0 at NK-2.

#define GATEN(n) asm volatile("s_waitcnt vmcnt(" #n ")" ::: "memory")
#define NOGATE ((void)0)
#define NOSTG  ((void)0)
#define NORD   ((void)0)

#define SA_(PA, KO) do { \
  gl_lds16(aptr0 + (KO), &PA[wid * 16][0]);        \
  gl_lds16(aptr1 + (KO), &PA[64 + wid * 16][0]); } while (0)
#define SBALL(PB, KS) do { \
  gl_lds16(bptrT + (size_t)(KS) * 8192,        &PB[wid * 16][0]);        \
  gl_lds16(bptrT + (size_t)(KS) * 8192 + 2048, &PB[64 + wid * 16][0]);   \
  gl_lds16(bptrT + (size_t)(KS) * 8192 + 4096, &PB[128 + wid * 16][0]);  \
  gl_lds16(bptrT + (size_t)(KS) * 8192 + 6144, &PB[192 + wid * 16][0]); } while (0)

#define RDAF8(P)                                                        \
  _Pragma("unroll")                                                     \
  for (int i_ = 0; i_ < 8; ++i_)                                        \
    af[i_] = *(const bf16x8*)&P[i_ * 16 + lrow][sp8]
#define RDBF(P)                                                         \
  _Pragma("unroll")                                                     \
  for (int n_ = 0; n_ < 4; ++n_)                                        \
    bfr[n_] = *(const bf16x8*)&P[wn + n_ * 16 + lrow][sp8]

#define PHF(STG, GATE, RD) do {                                         \
  STG;                                                                  \
  GATE;                                                                 \
  __builtin_amdgcn_s_barrier();                                         \
  asm volatile("s_waitcnt lgkmcnt(0)" ::: "memory");                    \
  __builtin_amdgcn_sched_barrier(0);                                    \
  __builtin_amdgcn_s_setprio(1);                                        \
  _Pragma("unroll")                                                     \
  for (int nf = 0; nf < 4; ++nf)                                        \
    _Pragma("unroll")                                                   \
    for (int mf = 0; mf < 8; ++mf)                                      \
      acc[nf][mf] = __builtin_amdgcn_mfma_f32_16x16x32_bf16(            \
          bfr[nf], af[mf], acc[nf][mf], 0, 0, 0);                       \
  __builtin_amdgcn_s_setprio(0);                                        \
  RD;                                                                   \
  __builtin_amdgcn_sched_barrier(0);                                    \
} while (0)

template<int MODE, int EPI>
__global__ __launch_bounds__(256, 2) void gemm_tb(
    const u16* __restrict__ Wt, const float* __restrict__ bias,
    const u16* __restrict__ Abase,
    u16* __restrict__ Hout, u16* __restrict__ Ybuf, float* __restrict__ Out,
    const int* __restrict__ slot_token, const float* __restrict__ slot_wt,
    const int* __restrict__ tile_e, const int* __restrict__ meta,
    int tile0, int mtc)
{
  constexpr int KD = (MODE == 0) ? DM : DH;
  constexpr int ND = (MODE == 0) ? DH : DM;
  constexpr int NT = ND / 256;
  constexpr int NK = KD / 32;

  __shared__ u16 A_s[3][128][32];   // [buf][row][32 bf16], 4x16B slots/row
  __shared__ u16 B_s[3][256][32];

  int nwg = gridDim.x;
  int flat = blockIdx.x;
  int q8 = nwg >> 3, rr = nwg & 7;
  int xcd = flat & 7, i0 = flat >> 3;
  int wg = (xcd < rr ? xcd * (q8 + 1) : rr * (q8 + 1) + (xcd - rr) * q8) + i0;
  // mloc-major: the NT n-tile blocks of one m-tile are consecutive -> concurrent
  int mloc = wg / NT;
  int ntile = wg % NT;
  int mt = tile0 + mloc;
  if (mt >= meta[0]) return;
  int e = tile_e[mt];
  int n0 = ntile * 256;

  const int tid = threadIdx.x;
  const int lane = tid & 63;
  const int wid = tid >> 6;
  const int lrow = lane & 15;
  const int g = lane >> 4;
  const int sp8 = (g ^ ((lrow >> 1) & 3)) << 3;   // swizzled 16B slot (read side)
  const int wn = wid << 6;                        // 0 / 64 / 128 / 192

  // A staging: thread stages rows srow(+64); source pre-swizzled (rule 21)
  const int srow = tid >> 2;
  const int swz = ((tid & 3) ^ ((tid >> 3) & 3)) << 3;

  const u16 *aptr0, *aptr1;
  if (MODE == 0) {
    int t0 = slot_token[mt * 128 + srow];       if (t0 < 0) t0 = 0;
    int t1 = slot_token[mt * 128 + 64 + srow];  if (t1 < 0) t1 = 0;
    aptr0 = Abase + (size_t)t0 * KD + swz;
    aptr1 = Abase + (size_t)t1 * KD + swz;
  } else {
    aptr0 = Abase + (size_t)(mloc * 128 + srow) * KD + swz;
    aptr1 = Abase + (size_t)(mloc * 128 + 64 + srow) * KD + swz;
  }
  // B staging: blocked layout, 16 KB contiguous per k-step, base + tid*16B
  const u16* bptrT = Wt + ((size_t)(e * NT + ntile) * NK) * 8192 + tid * 8;

  f32x4 acc[4][8] = {};   // [nf][mf], D^T (operand-swapped); wave owns full 128 M
  bf16x8 af[8], bfr[4];

  u16 (*pA0)[32] = A_s[0]; u16 (*pA1)[32] = A_s[1]; u16 (*pA2)[32] = A_s[2];
  u16 (*pB0)[32] = B_s[0]; u16 (*pB1)[32] = B_s[1]; u16 (*pB2)[32] = B_s[2];

  // prologue: stage steps 0,1 (12 loads), drain step0, preload step0 frags
  SA_(pA0, 0); SBALL(pB0, 0);
  SA_(pA1, 32); SBALL(pB1, 1);
  GATEN(6);
  __builtin_amdgcn_s_barrier();
  __builtin_amdgcn_sched_barrier(0);
  RDAF8(pA0);
  RDBF(pB0);

  for (int t = 0; t < NK - 2; ++t) {
    int ko = (t + 2) * 32;
    // fat phase: MFMA step t; stage step t+2 -> pA2/pB2; read frags step t+1
    PHF(SA_(pA2, ko); SBALL(pB2, t + 2), GATEN(6),
        RDAF8(pA1); RDBF(pB1));
    // rotate cur<-next<-nn<-cur
    u16 (*tA)[32] = pA0; pA0 = pA1; pA1 = pA2; pA2 = tA;
    u16 (*tB)[32] = pB0; pB0 = pB1; pB1 = pB2; pB2 = tB;
  }
  // tail: step NK-2 (drain last loads before reading step NK-1 frags), step NK-1
  PHF(NOSTG, GATEN(0), RDAF8(pA1); RDBF(pB1));
  PHF(NOSTG, NOGATE, NORD);

  // epilogue: n = n0 + wn + nf*16 + rb + i ; row = mf*16 + lrow (wave owns all M)
  const int rb = g << 2;
  float4 bias4[4];
#pragma unroll
  for (int nf = 0; nf < 4; ++nf)
    bias4[nf] = *(const float4*)&bias[e * ND + n0 + wn + nf * 16 + rb];

  if constexpr (MODE == 0) {
#pragma unroll
    for (int mf = 0; mf < 8; ++mf) {
      u16* hp = Hout + (size_t)(mloc * 128 + mf * 16 + lrow) * DH + n0 + wn + rb;
#pragma unroll
      for (int nf = 0; nf < 4; ++nf) {
        float v0 = gelu_f(acc[nf][mf][0] + bias4[nf].x);
        float v1 = gelu_f(acc[nf][mf][1] + bias4[nf].y);
        float v2 = gelu_f(acc[nf][mf][2] + bias4[nf].z);
        float v3 = gelu_f(acc[nf][mf][3] + bias4[nf].w);
        uint2 pk;
        pk.x = f2bf(v0) | ((u32)f2bf(v1) << 16);
        pk.y = f2bf(v2) | ((u32)f2bf(v3) << 16);
        *(uint2*)(hp + nf * 16) = pk;
      }
    }
  } else if constexpr (EPI == 0) {
#pragma unroll
    for (int mf = 0; mf < 8; ++mf) {
      u16* yp = Ybuf + (size_t)(mt * 128 + mf * 16 + lrow) * DM + n0 + wn + rb;
#pragma unroll
      for (int nf = 0; nf < 4; ++nf) {
        float v0 = acc[nf][mf][0] + bias4[nf].x;
        float v1 = acc[nf][mf][1] + bias4[nf].y;
        float v2 = acc[nf][mf][2] + bias4[nf].z;
        float v3 = acc[nf][mf][3] + bias4[nf].w;
        uint2 pk;
        pk.x = f2bf(v0) | ((u32)f2bf(v1) << 16);
        pk.y = f2bf(v2) | ((u32)f2bf(v3) << 16);
        *(uint2*)(yp + nf * 16) = pk;
      }
    }
  } else {
#pragma unroll
    for (int mf = 0; mf < 8; ++mf) {
      int gs = mt * 128 + mf * 16 + lrow;
      int tok = slot_token[gs];
      if (tok < 0) continue;
      float wt = slot_wt[gs];
      float* op = Out + (size_t)tok * DM + n0 + wn + rb;
#pragma unroll
      for (int nf = 0; nf < 4; ++nf) {
        atomicAdd(op + nf * 16 + 0, wt * (acc[nf][mf][0] + bias4[nf].x));
        atomicAdd(op + nf * 16 + 1, wt * (acc[nf][mf][1] + bias4[nf].y));
        atomicAdd(op + nf * 16 + 2, wt * (acc[nf][mf][2] + bias4[nf].z));
        atomicAdd(op + nf * 16 + 3, wt * (acc[nf][mf][3] + bias4[nf].w));
      }
    }
  }
}

// ---------------- combine: out[t] = w0*y[s0] + w1*y[s1] ----------------
__global__ __launch_bounds__(256) void combine_kernel(
    const u16* __restrict__ y, const int* __restrict__ tok_slots,
    const float* __restrict__ top_w, float* __restrict__ out)
{
  int t = blockIdx.x;
  int d = threadIdx.x * 8;
  int s0 = tok_slots[t * 2], s1 = tok_slots[t * 2 + 1];
  float w0 = top_w[t * 2], w1 = top_w[t * 2 + 1];
  union { uint4 u; u16 s[8]; } a, b;
  a.u = *(const uint4*)(y + (size_t)s0 * DM + d);
  b.u = *(const uint4*)(y + (size_t)s1 * DM + d);
  float o[8];
#pragma unroll
  for (int j = 0; j < 8; ++j) o[j] = w0 * bf2f(a.s[j]) + w1 * bf2f(b.s[j]);
  float* op = out + (size_t)t * DM + d;
  *(float4*)op = make_float4(o[0], o[1], o[2], o[3]);
  *(float4*)(op + 4) = make_float4(o[4], o[5], o[6], o[7]);
}

extern "C" void kernel_launch(void* const* d_in, const int* in_sizes, int n_in,
                              void* d_out, int out_size, void* d_ws, size_t ws_size,
                              hipStream_t stream) {
  const float* x  = (const float*)d_in[0];
  const float* rw = (const float*)d_in[1];
  const float* w1 = (const float*)d_in[2];
  const float* b1 = (const float*)d_in[3];
  const float* w2 = (const float*)d_in[4];
  const float* b2 = (const float*)d_in[5];
  float* out = (float*)d_out;
  char* ws = (char*)d_ws;

  int* counts = (int*)ws;
  int* meta   = (int*)(ws + OFF_META);
  int* tile_e = (int*)(ws + OFF_TILEE);
  int* top_e  = (int*)(ws + OFF_TOPE);
  float* top_w = (float*)(ws + OFF_TOPW);
  int* slot_token = (int*)(ws + OFF_SLOTT);
  int* tok_slots  = (int*)(ws + OFF_UNION);
  float* slot_wt  = (float*)(ws + OFF_UNION);
  u16* xbf = (u16*)(ws + OFF_XBF);
  u16* w1t = (u16*)(ws + OFF_W1T);
  u16* w2t = (u16*)(ws + OFF_W2T);

  const int useY = (ws_size >= NEED_Y) ? 1 : 0;
  u16* ybuf = (u16*)(ws + OFF_Y);
  u16* hbuf = (u16*)(ws + (useY ? OFF_H3 : OFF_Y));

  hipMemsetAsync(ws, 0, 512, stream);
  if (!useY) hipMemsetAsync(d_out, 0, (size_t)out_size * sizeof(float), stream);

  prep_kernel<<<9216, 256, 0, stream>>>(x, rw, w1, w2, counts, top_e, top_w,
                                        xbf, w1t, w2t);
  scan_scatter_kernel<<<1, 256, 0, stream>>>((int*)ws, useY);

  size_t hoff = useY ? OFF_H3 : OFF_Y;
  size_t avail = ws_size > hoff ? ws_size - hoff : (size_t)DH * 256;
  long ch_slots = (long)(avail / (DH * 2));
  ch_slots = (ch_slots / 128) * 128;
  if (ch_slots > MAXSLOT) ch_slots = MAXSLOT;
  if (ch_slots < 128) ch_slots = 128;
  int mtc = (int)(ch_slots / 128);
  int nchunks = (MAXTILE + mtc - 1) / mtc;

  for (int c = 0; c < nchunks; ++c) {
    int tile0 = c * mtc;
    gemm_tb<0, 0><<<dim3(mtc * (DH / 256)), 256, 0, stream>>>(
        w1t, b1, xbf, hbuf, nullptr, nullptr, slot_token, slot_wt, tile_e, meta,
        tile0, mtc);
    if (useY) {
      gemm_tb<1, 0><<<dim3(mtc * (DM / 256)), 256, 0, stream>>>(
          w2t, b2, hbuf, nullptr, ybuf, nullptr, slot_token, slot_wt, tile_e, meta,
          tile0, mtc);
    } else {
      gemm_tb<1, 1><<<dim3(mtc * (DM / 256)), 256, 0, stream>>>(
          w2t, b2, hbuf, nullptr, nullptr, out, slot_token, slot_wt, tile_e, meta,
          tile0, mtc);
    }
  }
  if (useY)
    combine_kernel<<<T_TOK, 256, 0, stream>>>(ybuf, tok_slots, top_w, out);
}